// Round 9
// baseline (3943.201 us; speedup 1.0000x reference)
//
#include <hip/hip_runtime.h>
#include <hip/hip_bf16.h>
#include <stdint.h>

// Problem constants (fixed by the reference)
#define TT 32768   // total tokens
#define DD 2048    // model dim
#define HH 5632    // hidden dim
#define NE 8       // experts

typedef __bf16 bf16;
typedef __bf16 bf16x8 __attribute__((ext_vector_type(8)));
typedef float  f32x4  __attribute__((ext_vector_type(4)));

__device__ __forceinline__ void gl16(const void* g, void* l) {
    __builtin_amdgcn_global_load_lds(
        (const __attribute__((address_space(1))) void*)g,
        (__attribute__((address_space(3))) void*)l, 16, 0, 0);
}
#define VMW(n) asm volatile("s_waitcnt vmcnt(" #n ")" ::: "memory")
#define LGKM0() do { asm volatile("s_waitcnt lgkmcnt(0)" ::: "memory"); \
                     __builtin_amdgcn_sched_barrier(0); } while (0)
#define BARRIER() __builtin_amdgcn_s_barrier()

// LDS XOR-swizzle for 64-B rows: measured 0 bank conflicts (r2-r8).
__device__ __forceinline__ int swz(int off) { return off ^ (((off >> 7) & 3) << 4); }

__device__ __forceinline__ int expert_of(const int* counts, int row0) {
    int base = 0;
    for (int i = 0; i < NE; ++i) { int c = counts[i]; if (row0 < base + c) return i; base += c; }
    return NE - 1;
}

// ---------------- f32 -> bf16 convert ----------------
__global__ __launch_bounds__(256)
void k_cvt(const float* __restrict__ in, bf16* __restrict__ out, long n) {
    long i = ((long)blockIdx.x * 256 + threadIdx.x) * 8;
    const long stride = (long)gridDim.x * 256 * 8;
    for (; i < n; i += stride) {
        const float4* p = (const float4*)(in + i);
        float4 a = p[0], b = p[1];
        union { bf16 v[8]; uint4 u; } r;
        r.v[0] = (bf16)a.x; r.v[1] = (bf16)a.y; r.v[2] = (bf16)a.z; r.v[3] = (bf16)a.w;
        r.v[4] = (bf16)b.x; r.v[5] = (bf16)b.y; r.v[6] = (bf16)b.z; r.v[7] = (bf16)b.w;
        *(uint4*)(out + i) = r.u;
    }
}

// =====================================================================
// Persistent fused GEMM1, 256-thread / 2-blocks-per-CU variant.
// BM=128 tokens x 64 hidden (per matrix), BK=32. 4 waves (2M x 2N),
// wave = 64M x 32N per matrix. LDS: 5 buffers x 16 KiB (A 8K | B1 4K |
// B3 4K) = 80 KiB -> 2 blocks/CU (two independent barrier groups
// desync -> LDS drain of one overlaps MFMA of the other, m114).
// Books identical to r8: 4 gloads/tile, stage lead 4, VMW(8) steady,
// boundary switch at tc==60, epilogue after pair tc==62, tail once.
// Persistent: grid=512 (2/CU), 44 segments; mt FIXED per block.
// =====================================================================
#define M1_LOAD(bufb, NA, NB1, NB3) do {                                      \
    const char* nb_ = sm + (bufb);                                            \
    _Pragma("unroll")                                                         \
    for (int mi = 0; mi < 4; ++mi)                                            \
        NA[mi] = *(const bf16x8*)(nb_ + aoff0 + mi * 1024);                   \
    _Pragma("unroll")                                                         \
    for (int ni = 0; ni < 2; ++ni) {                                          \
        NB1[ni] = *(const bf16x8*)(nb_ + 8192 + boff0 + ni * 1024);           \
        NB3[ni] = *(const bf16x8*)(nb_ + 12288 + boff0 + ni * 1024);          \
    }                                                                         \
    __builtin_amdgcn_sched_barrier(0);                                        \
} while (0)

#define M1_ITER(g, bLb, bSb, ko, CA, CB1, CB3, NA, NB1, NB3) do {             \
    if ((g) + 4 < GTOT) { stage((ko), (bSb)); VMW(8); }                       \
    else if ((g) == GTOT - 4) { VMW(4); }                                     \
    else if ((g) == GTOT - 3) { VMW(0); }                                     \
    LGKM0();                                                                  \
    if ((g) + 1 < GTOT) M1_LOAD((bLb), NA, NB1, NB3);                         \
    __builtin_amdgcn_s_setprio(1);                                            \
    _Pragma("unroll")                                                         \
    for (int mi = 0; mi < 4; ++mi)                                            \
    _Pragma("unroll")                                                         \
    for (int ni = 0; ni < 2; ++ni) {                                          \
        acc1[mi][ni] = __builtin_amdgcn_mfma_f32_16x16x32_bf16(CA[mi], CB1[ni], acc1[mi][ni], 0, 0, 0); \
        acc3[mi][ni] = __builtin_amdgcn_mfma_f32_16x16x32_bf16(CA[mi], CB3[ni], acc3[mi][ni], 0, 0, 0); \
    }                                                                         \
    __builtin_amdgcn_s_setprio(0);                                            \
    BARRIER();                                                                \
} while (0)

__global__ __launch_bounds__(256, 2)
void k_moe1(const bf16* __restrict__ xb, const bf16* __restrict__ w1b,
            const bf16* __restrict__ w3b, const int* __restrict__ counts,
            bf16* __restrict__ h) {
    extern __shared__ __align__(16) char sm[];
    const int tid = threadIdx.x;
    const int c = blockIdx.x & 7;      // XCD (round-robin dispatch)
    const int j = blockIdx.x >> 3;     // [0,64) position within XCD
    const int NSEG = 44;
    const int NT = 64;                 // DD/32
    const int GTOT = NSEG * NT;        // 2816

    // mt fixed per block: expert c <-> XCD c; A panel (512 KB) L2/L3-warm.
    // nt = seg*2 + (j>>5): concurrent blocks share ~1 MB of W1+W3 (L2).
    const int mt = (c << 5) + (j & 31);
    const int row0 = mt * 128;
    const int e = expert_of(counts, row0);

    const int s0 = swz(tid * 16);          // A rows [0,64)  (swizzled)
    const int s1 = 4096 + s0;              // A rows [64,128)
    const int dst0 = tid * 16;

    const char* sa0 = (const char*)xb + (((size_t)(row0 + (s0 >> 6)) * DD) << 1) + (s0 & 63);
    const char* sa1 = (const char*)xb + (((size_t)(row0 + (s1 >> 6)) * DD) << 1) + (s1 & 63);
    const char* w1p = (const char*)(w1b + (size_t)e * HH * DD);
    const char* w3p = (const char*)(w3b + (size_t)e * HH * DD);
    const char *sa2, *sa3;
    int sseg = 0;
    auto set_b = [&](int sg) {
        int c0 = (sg * 2 + (j >> 5)) * 64;
        sa2 = w1p + (((size_t)(c0 + (s0 >> 6)) * DD) << 1) + (s0 & 63);
        sa3 = w3p + (((size_t)(c0 + (s0 >> 6)) * DD) << 1) + (s0 & 63);
    };
    set_b(0);

    auto stage = [&](int ko, int bufb) {
        char* db = sm + bufb;
        gl16(sa0 + ko, db + dst0);
        gl16(sa1 + ko, db + 4096 + dst0);
        gl16(sa2 + ko, db + 8192 + dst0);
        gl16(sa3 + ko, db + 12288 + dst0);
    };

    const int lane = tid & 63, wv = tid >> 6;
    const int wrow = wv >> 1, wcol = wv & 1;     // wave = 64 rows x 32 cols/mat
    const int lrow = lane & 15, kb = (lane >> 4) << 4;
    const int aoff0 = swz((wrow * 64 + lrow) * 64 + kb);   // + mi*1024
    const int boff0 = swz((wcol * 32 + lrow) * 64 + kb);   // + ni*1024

    f32x4 acc1[4][2] = {};
    f32x4 acc3[4][2] = {};
    bf16x8 Xa[4], Xb1[2], Xb3[2], Ya[4], Yb1[2], Yb3[2];

    // prologue: tiles 0..3 of seg 0 into buffers 0..3 (16 KiB each)
    stage(0, 0); stage(64, 16384); stage(128, 32768); stage(192, 49152);
    VMW(8);            // tiles 0,1 landed
    BARRIER();
    M1_LOAD(0, Xa, Xb1, Xb3);

    int tc = 0, stk = 256, b0 = 0;
    int cseg = 0;
    int ccol0 = (j >> 5) * 64;

    for (int gp = 0; gp < GTOT; gp += 2) {
        int bL1 = b0 + 1; if (bL1 >= 5) bL1 -= 5;
        int bL2 = b0 + 2; if (bL2 >= 5) bL2 -= 5;
        int bS1 = b0 + 4; if (bS1 >= 5) bS1 -= 5;
        const int bS2 = b0;
        if (tc == 60 && sseg + 1 < NSEG) { ++sseg; set_b(sseg); stk = 0; }

        M1_ITER(gp,     bL1 << 14, bS1 << 14, stk,      Xa, Xb1, Xb3, Ya, Yb1, Yb3);
        M1_ITER(gp + 1, bL2 << 14, bS2 << 14, stk + 64, Ya, Yb1, Yb3, Xa, Xb1, Xb3);
        stk += 128;
        b0 += 2; if (b0 >= 5) b0 -= 5;

        if (tc == 62) {
            // segment epilogue: bf16-round h1,h3, silu in f32, bf16 h
#pragma unroll
            for (int mi = 0; mi < 4; ++mi)
#pragma unroll
                for (int ni = 0; ni < 2; ++ni) {
#pragma unroll
                    for (int jj = 0; jj < 4; ++jj) {
                        int row = row0 + wrow * 64 + mi * 16 + ((lane >> 4) << 2) + jj;
                        int col = ccol0 + wcol * 32 + ni * 16 + lrow;
                        float f1 = (float)(bf16)acc1[mi][ni][jj];
                        float f3 = (float)(bf16)acc3[mi][ni][jj];
                        float s = f1 / (1.0f + __expf(-f1));
                        h[(size_t)row * HH + col] = (bf16)(s * f3);
                    }
                    acc1[mi][ni] = (f32x4){0.f, 0.f, 0.f, 0.f};
                    acc3[mi][ni] = (f32x4){0.f, 0.f, 0.f, 0.f};
                }
            ++cseg;
            ccol0 = (cseg * 2 + (j >> 5)) * 64;
            tc = 0;
        } else {
            tc += 2;
        }
    }
}

// =====================================================================
// GEMM2, 256-thread / 2-blocks-per-CU, non-persistent static loop
// (r5-proven form). BM=BN=128, BK=32, NT=176, grid=4096.
// 4 waves (2M x 2N), wave = 64 x 64. LDS buffer: A 8K | B 8K.
// mt = 32c + (local&31) fast, nt = local>>5 slow -> concurrent blocks
// share ~2.9 MB of W2 (L2-resident).
// =====================================================================
#define G2_LOAD(t1, NA, NB) do {                                              \
    const char* nb_ = sm + (size_t)((t1) % 5) * 16384;                        \
    _Pragma("unroll")                                                         \
    for (int mi = 0; mi < 4; ++mi)                                            \
        NA[mi] = *(const bf16x8*)(nb_ + aoff0 + mi * 1024);                   \
    _Pragma("unroll")                                                         \
    for (int ni = 0; ni < 4; ++ni)                                            \
        NB[ni] = *(const bf16x8*)(nb_ + 8192 + boff0 + ni * 1024);            \
    __builtin_amdgcn_sched_barrier(0);                                        \
} while (0)

#define G2_ITER(t, CA, CB, NA, NB) do {                                       \
    if ((t) + 4 < NT) { stage((t) + 4); VMW(8); }                             \
    else if ((t) == NT - 4) { VMW(4); }                                       \
    else if ((t) == NT - 3) { VMW(0); }                                       \
    LGKM0();                                                                  \
    if ((t) + 1 < NT) G2_LOAD((t) + 1, NA, NB);                               \
    __builtin_amdgcn_s_setprio(1);                                            \
    _Pragma("unroll")                                                         \
    for (int mi = 0; mi < 4; ++mi)                                            \
    _Pragma("unroll")                                                         \
    for (int ni = 0; ni < 4; ++ni)                                            \
        acc[mi][ni] = __builtin_amdgcn_mfma_f32_16x16x32_bf16(CA[mi], CB[ni], acc[mi][ni], 0, 0, 0); \
    __builtin_amdgcn_s_setprio(0);                                            \
    BARRIER();                                                                \
} while (0)

__global__ __launch_bounds__(256, 2)
void k_g2(const bf16* __restrict__ hb, const bf16* __restrict__ w2b,
          const int* __restrict__ counts, float* __restrict__ out) {
    extern __shared__ __align__(16) char sm[];
    const int tid = threadIdx.x;
    const int c = blockIdx.x & 7;
    const int local = blockIdx.x >> 3;            // [0,512)
    const int mt = (c << 5) + (local & 31);       // fast: expert c rows
    const int nt = local >> 5;                    // slow: [0,16)
    const int row0 = mt * 128, col0 = nt * 128;
    const int e = expert_of(counts, row0);

    const int s0 = swz(tid * 16);
    const int s1 = 4096 + s0;
    const int dst0 = tid * 16;

    const char* sa0 = (const char*)hb + (((size_t)(row0 + (s0 >> 6)) * HH) << 1) + (s0 & 63);
    const char* sa1 = (const char*)hb + (((size_t)(row0 + (s1 >> 6)) * HH) << 1) + (s1 & 63);
    const char* wp = (const char*)(w2b + (size_t)e * DD * HH);
    const char* sa2 = wp + (((size_t)(col0 + (s0 >> 6)) * HH) << 1) + (s0 & 63);
    const char* sa3 = wp + (((size_t)(col0 + (s1 >> 6)) * HH) << 1) + (s1 & 63);

    auto stage = [&](int kt) {
        char* db = sm + (size_t)(kt % 5) * 16384;
        const size_t ko = (size_t)kt << 6;
        gl16(sa0 + ko, db + dst0);
        gl16(sa1 + ko, db + 4096 + dst0);
        gl16(sa2 + ko, db + 8192 + dst0);
        gl16(sa3 + ko, db + 12288 + dst0);
    };

    const int lane = tid & 63, wv = tid >> 6;
    const int wrow = wv >> 1, wcol = wv & 1;      // wave = 64 x 64
    const int lrow = lane & 15, kb = (lane >> 4) << 4;
    const int aoff0 = swz((wrow * 64 + lrow) * 64 + kb);   // + mi*1024
    const int boff0 = swz((wcol * 64 + lrow) * 64 + kb);   // + ni*1024

    f32x4 acc[4][4] = {};
    bf16x8 Xa[4], Xb[4], Ya[4], Yb[4];

    const int NT = HH / 32;   // 176
    stage(0); stage(1); stage(2); stage(3);
    VMW(8);
    BARRIER();
    G2_LOAD(0, Xa, Xb);
    for (int t = 0; t < NT; t += 2) {
        G2_ITER(t,     Xa, Xb, Ya, Yb);
        G2_ITER(t + 1, Ya, Yb, Xa, Xb);
    }

#pragma unroll
    for (int mi = 0; mi < 4; ++mi)
#pragma unroll
        for (int ni = 0; ni < 4; ++ni)
#pragma unroll
            for (int j = 0; j < 4; ++j) {
                int row = row0 + wrow * 64 + mi * 16 + ((lane >> 4) << 2) + j;
                int col = col0 + wcol * 64 + ni * 16 + lrow;
                out[(size_t)row * DD + col] = (float)(bf16)acc[mi][ni][j];
            }
}

extern "C" void kernel_launch(void* const* d_in, const int* in_sizes, int n_in,
                              void* d_out, int out_size, void* d_ws, size_t ws_size,
                              hipStream_t stream) {
    const float* x      = (const float*)d_in[0];
    const float* w1     = (const float*)d_in[1];
    const float* w2     = (const float*)d_in[2];
    const float* w3     = (const float*)d_in[3];
    const int*   counts = (const int*)d_in[4];
    float* out = (float*)d_out;

    const size_t xb_b = (size_t)TT * DD * 2;        // 128 MiB
    const size_t h_b  = (size_t)TT * HH * 2;        // 352 MiB
    const size_t w_b  = (size_t)NE * HH * DD * 2;   // 176 MiB each
    const size_t need_full = xb_b + h_b + 2 * w_b;  // 832 MiB (proven available)
    if (ws_size < need_full) return;

    bf16* xb  = (bf16*)d_ws;
    bf16* h   = (bf16*)((char*)d_ws + xb_b);
    bf16* wsA = (bf16*)((char*)d_ws + xb_b + h_b);
    bf16* wsB = (bf16*)((char*)d_ws + xb_b + h_b + w_b);

    hipFuncSetAttribute((const void*)k_moe1, hipFuncAttributeMaxDynamicSharedMemorySize, 81920);
    hipFuncSetAttribute((const void*)k_g2,   hipFuncAttributeMaxDynamicSharedMemorySize, 81920);

    k_cvt<<<2048, 256, 0, stream>>>(x,  xb,  (long)TT * DD);
    k_cvt<<<2048, 256, 0, stream>>>(w1, wsA, (long)NE * HH * DD);
    k_cvt<<<2048, 256, 0, stream>>>(w3, wsB, (long)NE * HH * DD);
    k_moe1<<<512, 256, 81920, stream>>>(xb, wsA, wsB, counts, h);
    k_cvt<<<2048, 256, 0, stream>>>(w2, wsA, (long)NE * DD * HH);   // reuse slot A
    k_g2<<<4096, 256, 81920, stream>>>(h, wsA, counts, out);
}

// Round 10
// 2646.159 us; speedup vs baseline: 1.4902x; 1.4902x over previous
//
#include <hip/hip_runtime.h>
#include <hip/hip_bf16.h>
#include <stdint.h>

// Problem constants (fixed by the reference)
#define TT 32768   // total tokens
#define DD 2048    // model dim
#define HH 5632    // hidden dim
#define NE 8       // experts

typedef __bf16 bf16;
typedef __bf16 bf16x8 __attribute__((ext_vector_type(8)));
typedef float  f32x4  __attribute__((ext_vector_type(4)));

__device__ __forceinline__ void gl16(const void* g, void* l) {
    __builtin_amdgcn_global_load_lds(
        (const __attribute__((address_space(1))) void*)g,
        (__attribute__((address_space(3))) void*)l, 16, 0, 0);
}
#define VMW(n) asm volatile("s_waitcnt vmcnt(" #n ")" ::: "memory")
#define LGKM0() do { asm volatile("s_waitcnt lgkmcnt(0)" ::: "memory"); \
                     __builtin_amdgcn_sched_barrier(0); } while (0)
#define BARRIER() __builtin_amdgcn_s_barrier()
#define SGB(mask, n) __builtin_amdgcn_sched_group_barrier((mask), (n), 0)
// LLVM SchedGroupMask: MFMA=0x8, DS_READ=0x100

// LDS XOR-swizzle for 64-B rows: measured 0 bank conflicts (r2-r8).
__device__ __forceinline__ int swz(int off) { return off ^ (((off >> 7) & 3) << 4); }

__device__ __forceinline__ int expert_of(const int* counts, int row0) {
    int base = 0;
    for (int i = 0; i < NE; ++i) { int c = counts[i]; if (row0 < base + c) return i; base += c; }
    return NE - 1;
}

// ---------------- f32 -> bf16 convert ----------------
__global__ __launch_bounds__(256)
void k_cvt(const float* __restrict__ in, bf16* __restrict__ out, long n) {
    long i = ((long)blockIdx.x * 256 + threadIdx.x) * 8;
    const long stride = (long)gridDim.x * 256 * 8;
    for (; i < n; i += stride) {
        const float4* p = (const float4*)(in + i);
        float4 a = p[0], b = p[1];
        union { bf16 v[8]; uint4 u; } r;
        r.v[0] = (bf16)a.x; r.v[1] = (bf16)a.y; r.v[2] = (bf16)a.z; r.v[3] = (bf16)a.w;
        r.v[4] = (bf16)b.x; r.v[5] = (bf16)b.y; r.v[6] = (bf16)b.z; r.v[7] = (bf16)b.w;
        *(uint4*)(out + i) = r.u;
    }
}

// =====================================================================
// Persistent fused GEMM1 (r8 structure; r10 change: ds_read burst is
// un-pinned and a sched_group_barrier sequence interleaves DS_READ with
// the MFMA cluster -> LDS service trickles under MFMA instead of
// stalling wave issue in a post-barrier burst).
// grid=256, 22 segments/block, 5x32KiB LDS, stage lead 4, VMW(8).
// =====================================================================
#define M1_LOAD(bufb, NA, NB1, NB3) do {                                      \
    const char* nb_ = sm + (bufb);                                            \
    _Pragma("unroll")                                                         \
    for (int mi = 0; mi < 8; ++mi)                                            \
        NA[mi] = *(const bf16x8*)(nb_ + aoff0 + mi * 1024);                   \
    _Pragma("unroll")                                                         \
    for (int ni = 0; ni < 2; ++ni) {                                          \
        NB1[ni] = *(const bf16x8*)(nb_ + 16384 + boff0 + ni * 1024);          \
        NB3[ni] = *(const bf16x8*)(nb_ + 24576 + boff0 + ni * 1024);          \
    }                                                                         \
} while (0)

// interleave directives: 12 DS_READ woven through 32 MFMA
#define M1_SGB() do {                                                         \
    SGB(0x8, 2);                                                              \
    _Pragma("unroll")                                                         \
    for (int gq = 0; gq < 6; ++gq) { SGB(0x100, 2); SGB(0x8, 5); }            \
    __builtin_amdgcn_sched_barrier(0);                                        \
} while (0)

#define M1_ITER(g, bLb, bSb, ko, CA, CB1, CB3, NA, NB1, NB3) do {             \
    if ((g) + 4 < GTOT) { stage((ko), (bSb)); VMW(8); }                       \
    else if ((g) == GTOT - 4) { VMW(4); }                                     \
    else if ((g) == GTOT - 3) { VMW(0); }                                     \
    LGKM0();                                                                  \
    __builtin_amdgcn_s_setprio(1);                                            \
    if ((g) + 1 < GTOT) M1_LOAD((bLb), NA, NB1, NB3);                         \
    _Pragma("unroll")                                                         \
    for (int mi = 0; mi < 8; ++mi)                                            \
    _Pragma("unroll")                                                         \
    for (int ni = 0; ni < 2; ++ni) {                                          \
        acc1[mi][ni] = __builtin_amdgcn_mfma_f32_16x16x32_bf16(CA[mi], CB1[ni], acc1[mi][ni], 0, 0, 0); \
        acc3[mi][ni] = __builtin_amdgcn_mfma_f32_16x16x32_bf16(CA[mi], CB3[ni], acc3[mi][ni], 0, 0, 0); \
    }                                                                         \
    M1_SGB();                                                                 \
    __builtin_amdgcn_s_setprio(0);                                            \
    BARRIER();                                                                \
} while (0)

__global__ __launch_bounds__(512, 2)
void k_moe1(const bf16* __restrict__ xb, const bf16* __restrict__ w1b,
            const bf16* __restrict__ w3b, const int* __restrict__ counts,
            bf16* __restrict__ h) {
    extern __shared__ __align__(16) char sm[];
    const int tid = threadIdx.x;
    const int c = blockIdx.x & 7;      // XCD (round-robin dispatch)
    const int j = blockIdx.x >> 3;     // [0,32) position within XCD
    const int NSEG = 22;
    const int NT = 64;                 // DD/32
    const int GTOT = NSEG * NT;        // 1408

    const int s0 = swz(tid * 16);
    const int s1 = 8192 + s0;
    const int dst0 = tid * 16;

    const char *sa0, *sa1, *sa2, *sa3;
    int sseg = 0;
    auto set_bases = [&](int sg) {
        int local = sg * 32 + j;
        int r0 = ((c << 4) + (local & 15)) * 256;
        int c0 = (local >> 4) * 128;
        int e = expert_of(counts, r0);
        sa0 = (const char*)xb + (((size_t)(r0 + (s0 >> 6)) * DD) << 1) + (s0 & 63);
        sa1 = (const char*)xb + (((size_t)(r0 + (s1 >> 6)) * DD) << 1) + (s1 & 63);
        const char* w1p = (const char*)(w1b + (size_t)e * HH * DD);
        const char* w3p = (const char*)(w3b + (size_t)e * HH * DD);
        sa2 = w1p + (((size_t)(c0 + (s0 >> 6)) * DD) << 1) + (s0 & 63);
        sa3 = w3p + (((size_t)(c0 + (s0 >> 6)) * DD) << 1) + (s0 & 63);
    };
    set_bases(0);

    auto stage = [&](int ko, int bufb) {
        char* db = sm + bufb;
        gl16(sa0 + ko, db + dst0);
        gl16(sa1 + ko, db + 8192 + dst0);
        gl16(sa2 + ko, db + 16384 + dst0);
        gl16(sa3 + ko, db + 24576 + dst0);
    };

    const int lane = tid & 63, wv = tid >> 6;
    const int wrow = wv >> 2, wcol = wv & 3;
    const int lrow = lane & 15, kb = (lane >> 4) << 4;
    const int aoff0 = swz((wrow * 128 + lrow) * 64 + kb);
    const int boff0 = swz((wcol * 32 + lrow) * 64 + kb);

    f32x4 acc1[8][2] = {};
    f32x4 acc3[8][2] = {};
    bf16x8 Xa[8], Xb1[2], Xb3[2], Ya[8], Yb1[2], Yb3[2];

    stage(0, 0); stage(64, 32768); stage(128, 65536); stage(192, 98304);
    VMW(8);
    BARRIER();
    M1_LOAD(0, Xa, Xb1, Xb3);

    int tc = 0, stk = 256, b0 = 0;
    int cseg = 0;
    int crow0 = ((c << 4) + (j & 15)) * 256;
    int ccol0 = (j >> 4) * 128;

    for (int gp = 0; gp < GTOT; gp += 2) {
        int bL1 = b0 + 1; if (bL1 >= 5) bL1 -= 5;
        int bL2 = b0 + 2; if (bL2 >= 5) bL2 -= 5;
        int bS1 = b0 + 4; if (bS1 >= 5) bS1 -= 5;
        const int bS2 = b0;
        if (tc == 60 && sseg + 1 < NSEG) { ++sseg; set_bases(sseg); stk = 0; }

        M1_ITER(gp,     bL1 << 15, bS1 << 15, stk,      Xa, Xb1, Xb3, Ya, Yb1, Yb3);
        M1_ITER(gp + 1, bL2 << 15, bS2 << 15, stk + 64, Ya, Yb1, Yb3, Xa, Xb1, Xb3);
        stk += 128;
        b0 += 2; if (b0 >= 5) b0 -= 5;

        if (tc == 62) {
#pragma unroll
            for (int mi = 0; mi < 8; ++mi)
#pragma unroll
                for (int ni = 0; ni < 2; ++ni) {
#pragma unroll
                    for (int jj = 0; jj < 4; ++jj) {
                        int row = crow0 + wrow * 128 + mi * 16 + ((lane >> 4) << 2) + jj;
                        int col = ccol0 + wcol * 32 + ni * 16 + lrow;
                        float f1 = (float)(bf16)acc1[mi][ni][jj];
                        float f3 = (float)(bf16)acc3[mi][ni][jj];
                        float s = f1 / (1.0f + __expf(-f1));
                        h[(size_t)row * HH + col] = (bf16)(s * f3);
                    }
                    acc1[mi][ni] = (f32x4){0.f, 0.f, 0.f, 0.f};
                    acc3[mi][ni] = (f32x4){0.f, 0.f, 0.f, 0.f};
                }
            ++cseg;
            int local = cseg * 32 + j;
            crow0 = ((c << 4) + (local & 15)) * 256;
            ccol0 = (local >> 4) * 128;
            tc = 0;
        } else {
            tc += 2;
        }
    }
}

// =====================================================================
// GEMM2 (r8 structure + SGB interleave). grid=1024, static NT=176 loop,
// mt-fast map (concurrent blocks share 2 W2 panels).
// =====================================================================
#define G2_LOAD(t1, NA, NB) do {                                              \
    const char* nb_ = sm + (size_t)((t1) % 5) * 32768;                        \
    _Pragma("unroll")                                                         \
    for (int mi = 0; mi < 8; ++mi)                                            \
        NA[mi] = *(const bf16x8*)(nb_ + aoff0 + mi * 1024);                   \
    _Pragma("unroll")                                                         \
    for (int ni = 0; ni < 4; ++ni)                                            \
        NB[ni] = *(const bf16x8*)(nb_ + 16384 + boff0 + ni * 1024);           \
} while (0)

// interleave: 12 DS_READ woven through 32 MFMA
#define G2_SGB() do {                                                         \
    SGB(0x8, 2);                                                              \
    _Pragma("unroll")                                                         \
    for (int gq = 0; gq < 6; ++gq) { SGB(0x100, 2); SGB(0x8, 5); }            \
    __builtin_amdgcn_sched_barrier(0);                                        \
} while (0)

#define G2_ITER(t, CA, CB, NA, NB) do {                                       \
    if ((t) + 4 < NT) { stage((t) + 4); VMW(8); }                             \
    else if ((t) == NT - 4) { VMW(4); }                                       \
    else if ((t) == NT - 3) { VMW(0); }                                       \
    LGKM0();                                                                  \
    __builtin_amdgcn_s_setprio(1);                                            \
    if ((t) + 1 < NT) G2_LOAD((t) + 1, NA, NB);                               \
    _Pragma("unroll")                                                         \
    for (int mi = 0; mi < 8; ++mi)                                            \
    _Pragma("unroll")                                                         \
    for (int ni = 0; ni < 4; ++ni)                                            \
        acc[mi][ni] = __builtin_amdgcn_mfma_f32_16x16x32_bf16(CA[mi], CB[ni], acc[mi][ni], 0, 0, 0); \
    G2_SGB();                                                                 \
    __builtin_amdgcn_s_setprio(0);                                            \
    BARRIER();                                                                \
} while (0)

__global__ __launch_bounds__(512, 2)
void k_g2(const bf16* __restrict__ hb, const bf16* __restrict__ w2b,
          const int* __restrict__ counts, float* __restrict__ out) {
    extern __shared__ __align__(16) char sm[];
    const int tid = threadIdx.x;
    const int c = blockIdx.x & 7;
    const int local = blockIdx.x >> 3;            // [0,128)
    const int nt = local >> 4;                    // slow (8 values)
    const int mt = (c << 4) + (local & 15);       // fast (16 per XCD)
    const int row0 = mt * 256, col0 = nt * 256;
    const int e = expert_of(counts, row0);

    const char *sa0, *sa1, *sa2, *sa3;
    {
        int off0 = tid * 16, off1 = 8192 + tid * 16;
        int s0 = swz(off0), s1 = swz(off1);
        sa0 = (const char*)hb + (((size_t)(row0 + (s0 >> 6)) * HH) << 1) + (s0 & 63);
        sa1 = (const char*)hb + (((size_t)(row0 + (s1 >> 6)) * HH) << 1) + (s1 & 63);
        const char* wp = (const char*)(w2b + (size_t)e * DD * HH);
        sa2 = wp + (((size_t)(col0 + (s0 >> 6)) * HH) << 1) + (s0 & 63);
        sa3 = wp + (((size_t)(col0 + (s1 >> 6)) * HH) << 1) + (s1 & 63);
    }
    const int dst0 = tid * 16;
    auto stage = [&](int kt) {
        char* db = sm + (size_t)(kt % 5) * 32768;
        const size_t ko = (size_t)kt << 6;
        gl16(sa0 + ko, db + dst0);
        gl16(sa1 + ko, db + 8192 + dst0);
        gl16(sa2 + ko, db + 16384 + dst0);
        gl16(sa3 + ko, db + 24576 + dst0);
    };

    const int lane = tid & 63, wv = tid >> 6;
    const int wrow = wv >> 2, wcol = wv & 3;      // wave = 128 x 64
    const int lrow = lane & 15, kb = (lane >> 4) << 4;

    const int aoff0 = swz((wrow * 128 + lrow) * 64 + kb);   // + mi*1024
    const int boff0 = swz((wcol * 64 + lrow) * 64 + kb);    // + ni*1024

    f32x4 acc[8][4] = {};
    bf16x8 Xa[8], Xb[4], Ya[8], Yb[4];

    const int NT = HH / 32;   // 176
    stage(0); stage(1); stage(2); stage(3);
    VMW(8);
    BARRIER();
    G2_LOAD(0, Xa, Xb);
    for (int t = 0; t < NT; t += 2) {
        G2_ITER(t,     Xa, Xb, Ya, Yb);
        G2_ITER(t + 1, Ya, Yb, Xa, Xb);
    }

#pragma unroll
    for (int mi = 0; mi < 8; ++mi)
#pragma unroll
        for (int ni = 0; ni < 4; ++ni)
#pragma unroll
            for (int j = 0; j < 4; ++j) {
                int row = row0 + wrow * 128 + mi * 16 + ((lane >> 4) << 2) + j;
                int col = col0 + wcol * 64 + ni * 16 + lrow;
                out[(size_t)row * DD + col] = (float)(bf16)acc[mi][ni][j];
            }
}

extern "C" void kernel_launch(void* const* d_in, const int* in_sizes, int n_in,
                              void* d_out, int out_size, void* d_ws, size_t ws_size,
                              hipStream_t stream) {
    const float* x      = (const float*)d_in[0];
    const float* w1     = (const float*)d_in[1];
    const float* w2     = (const float*)d_in[2];
    const float* w3     = (const float*)d_in[3];
    const int*   counts = (const int*)d_in[4];
    float* out = (float*)d_out;

    const size_t xb_b = (size_t)TT * DD * 2;        // 128 MiB
    const size_t h_b  = (size_t)TT * HH * 2;        // 352 MiB
    const size_t w_b  = (size_t)NE * HH * DD * 2;   // 176 MiB each
    const size_t need_full = xb_b + h_b + 2 * w_b;  // 832 MiB (proven available)
    if (ws_size < need_full) return;

    bf16* xb  = (bf16*)d_ws;
    bf16* h   = (bf16*)((char*)d_ws + xb_b);
    bf16* wsA = (bf16*)((char*)d_ws + xb_b + h_b);
    bf16* wsB = (bf16*)((char*)d_ws + xb_b + h_b + w_b);

    hipFuncSetAttribute((const void*)k_moe1, hipFuncAttributeMaxDynamicSharedMemorySize, 163840);
    hipFuncSetAttribute((const void*)k_g2,   hipFuncAttributeMaxDynamicSharedMemorySize, 163840);

    k_cvt<<<2048, 256, 0, stream>>>(x,  xb,  (long)TT * DD);
    k_cvt<<<2048, 256, 0, stream>>>(w1, wsA, (long)NE * HH * DD);
    k_cvt<<<2048, 256, 0, stream>>>(w3, wsB, (long)NE * HH * DD);
    k_moe1<<<256, 512, 163840, stream>>>(xb, wsA, wsB, counts, h);
    k_cvt<<<2048, 256, 0, stream>>>(w2, wsA, (long)NE * DD * HH);   // reuse slot A
    k_g2<<<1024, 512, 163840, stream>>>(h, wsA, counts, out);
}